// Round 2
// baseline (248.018 us; speedup 1.0000x reference)
//
#include <hip/hip_runtime.h>

#define S_LEN 2048
#define DMODEL 1024
#define NBATCH 4

typedef unsigned short u16;
typedef __bf16 bf16x8 __attribute__((ext_vector_type(8)));
typedef float f32x4 __attribute__((ext_vector_type(4)));

typedef __attribute__((address_space(3))) unsigned lds_u32;
typedef const __attribute__((address_space(1))) unsigned glb_u32;

__device__ __forceinline__ u16 f2bf(float f) {
  union { float f; unsigned u; } v;
  v.f = f;
  unsigned r = v.u + 0x7fffu + ((v.u >> 16) & 1u);
  return (u16)(r >> 16);
}

// ---------------- convert x: fp32 -> bf16, flat ----------------
__global__ void convert_x_kernel(const float* __restrict__ x, u16* __restrict__ xb, long n) {
  long i = ((long)blockIdx.x * blockDim.x + threadIdx.x) * 4;
  long stride = (long)gridDim.x * blockDim.x * 4;
  for (; i < n; i += stride) {
    float4 v = *reinterpret_cast<const float4*>(x + i);
    ushort4 o;
    o.x = f2bf(v.x); o.y = f2bf(v.y); o.z = f2bf(v.z); o.w = f2bf(v.w);
    *reinterpret_cast<ushort4*>(xb + i) = o;
  }
}

// ---------------- transpose-convert W: Wt[n][k] = bf16(W[k][n]), 1024x1024 ----------------
__global__ void transpose_w_kernel(const float* __restrict__ W, u16* __restrict__ Wt) {
  __shared__ float tile[32][33];
  int tx = threadIdx.x, ty = threadIdx.y;
  int k0 = blockIdx.x * 32, n0 = blockIdx.y * 32;
#pragma unroll
  for (int i = 0; i < 32; i += 8)
    tile[ty + i][tx] = W[(long)(k0 + ty + i) * DMODEL + n0 + tx];
  __syncthreads();
#pragma unroll
  for (int i = 0; i < 32; i += 8)
    Wt[(long)(n0 + ty + i) * DMODEL + k0 + tx] = f2bf(tile[tx][ty + i]);
}

// ---------------- NT GEMM: C[M][N] = A[M][K] * B[N][K]^T ----------------
// 128x128 tile, BK=32, 256 threads (4 waves in 2x2, each 64x64 via 4x4 16x16x32 MFMA frags)
// Staging: global_load_lds width=16 (m97 structure: 2 barriers / K-step, linear LDS).
// CMODE: 0 = f32 C row-major; 1 = bf16 C row-major; 2 = bf16 transposed write Vt[b][col][s]
// CAUSAL: 0 = none; 1 = skip blocks bn>bm (scores); 2 = K-limit (bm+1)*128 (PV)
template<int CMODE, int CAUSAL>
__global__ __launch_bounds__(256) void gemm_nt(
    const u16* __restrict__ A, const u16* __restrict__ B, void* __restrict__ Cptr,
    int lda, int ldb, int ldc, int Kdim,
    long sAz, long sBz, long sCz)
{
  int bm = blockIdx.x, bn = blockIdx.y, bz = blockIdx.z;
  if (CAUSAL == 1 && bn > bm) return;
  const u16* Ab = A + (long)bz * sAz + (long)(bm * 128) * lda;
  const u16* Bb = B + (long)bz * sBz + (long)(bn * 128) * ldb;
  int Keff = Kdim;
  if (CAUSAL == 2) { int lim = (bm + 1) * 128; if (lim < Keff) Keff = lim; }

  __shared__ u16 atile[128 * 32];
  __shared__ u16 btile[128 * 32];

  int tid = threadIdx.x;
  int lane = tid & 63, wave = tid >> 6;
  int wr = wave >> 1, wc = wave & 1;
  int l15 = lane & 15, lhi = lane >> 4;

  f32x4 zero = {0.f, 0.f, 0.f, 0.f};
  f32x4 acc[4][4];
#pragma unroll
  for (int m = 0; m < 4; ++m)
#pragma unroll
    for (int n = 0; n < 4; ++n) acc[m][n] = zero;

  // global_load_lds staging geometry: wave w stages rows [w*32, w*32+32) of each tile.
  // Per call: 64 lanes x 16B = 1024B = 16 rows (64B/row). lane -> row lane>>2, bytes (lane&3)*16.
  const int srow = wave * 32 + (lane >> 2);   // global/LDS row for chunk 0 (chunk 1: +16)
  const int scol = (lane & 3) * 8;            // element offset within row
  u16* lA = atile + wave * 1024;              // wave-uniform LDS dest (bytes: wave*2048)
  u16* lB = btile + wave * 1024;

  for (int k0 = 0; k0 < Keff; k0 += 32) {
    const u16* ga = Ab + (long)srow * lda + k0 + scol;
    const u16* gb = Bb + (long)srow * ldb + k0 + scol;
    __builtin_amdgcn_global_load_lds((glb_u32*)ga,               (lds_u32*)lA,         16, 0, 0);
    __builtin_amdgcn_global_load_lds((glb_u32*)(ga + 16 * lda),  (lds_u32*)(lA + 512), 16, 0, 0);
    __builtin_amdgcn_global_load_lds((glb_u32*)gb,               (lds_u32*)lB,         16, 0, 0);
    __builtin_amdgcn_global_load_lds((glb_u32*)(gb + 16 * ldb),  (lds_u32*)(lB + 512), 16, 0, 0);
    __syncthreads();   // compiler drains vmcnt before s_barrier -> tile visible

    bf16x8 af[4], bfr[4];
#pragma unroll
    for (int m = 0; m < 4; ++m)
      af[m] = *reinterpret_cast<const bf16x8*>(atile + (wr * 64 + m * 16 + l15) * 32 + lhi * 8);
#pragma unroll
    for (int n = 0; n < 4; ++n)
      bfr[n] = *reinterpret_cast<const bf16x8*>(btile + (wc * 64 + n * 16 + l15) * 32 + lhi * 8);
#pragma unroll
    for (int m = 0; m < 4; ++m)
#pragma unroll
      for (int n = 0; n < 4; ++n)
        acc[m][n] = __builtin_amdgcn_mfma_f32_16x16x32_bf16(af[m], bfr[n], acc[m][n], 0, 0, 0);
    __syncthreads();   // all waves done reading LDS before next iteration overwrites
  }

  int rowBase = bm * 128 + wr * 64;
  int colBase = bn * 128 + wc * 64;

  if constexpr (CMODE == 0) {
    float* C = (float*)Cptr + (long)bz * sCz;
#pragma unroll
    for (int m = 0; m < 4; ++m) {
      int rr = rowBase + m * 16 + lhi * 4;
#pragma unroll
      for (int n = 0; n < 4; ++n) {
        int col = colBase + n * 16 + l15;
#pragma unroll
        for (int r = 0; r < 4; ++r)
          C[(long)(rr + r) * ldc + col] = acc[m][n][r];
      }
    }
  } else if constexpr (CMODE == 1) {
    u16* C = (u16*)Cptr + (long)bz * sCz;
#pragma unroll
    for (int m = 0; m < 4; ++m) {
      int rr = rowBase + m * 16 + lhi * 4;
#pragma unroll
      for (int n = 0; n < 4; ++n) {
        int col = colBase + n * 16 + l15;
#pragma unroll
        for (int r = 0; r < 4; ++r)
          C[(long)(rr + r) * ldc + col] = f2bf(acc[m][n][r]);
      }
    }
  } else {
    // transposed V write: value at (row=s-global, col=e) -> Vt[b][e][s], 4 consecutive s per lane
    u16* C = (u16*)Cptr;
#pragma unroll
    for (int m = 0; m < 4; ++m) {
      int rr = rowBase + m * 16 + lhi * 4;
      int b = rr >> 11, s = rr & 2047;
#pragma unroll
      for (int n = 0; n < 4; ++n) {
        int col = colBase + n * 16 + l15;
        ushort4 v;
        v.x = f2bf(acc[m][n][0]); v.y = f2bf(acc[m][n][1]);
        v.z = f2bf(acc[m][n][2]); v.w = f2bf(acc[m][n][3]);
        *reinterpret_cast<ushort4*>(C + (long)b * (DMODEL * (long)S_LEN) + (long)col * S_LEN + s) = v;
      }
    }
  }
}

// ---------------- causal row softmax: scores(f32, unscaled) -> P(bf16, normalized) ----------------
__global__ __launch_bounds__(256) void softmax_row_kernel(const float* __restrict__ scores,
                                                          u16* __restrict__ P) {
  int q = blockIdx.x, b = blockIdx.y;
  const float* srow = scores + ((long)b * S_LEN + q) * S_LEN;
  u16* prow = P + ((long)b * S_LEN + q) * S_LEN;
  int n = q + 1;
  int tid = threadIdx.x;
  const float scale = 0.03125f; // 1/sqrt(1024)

  __shared__ float red[8];

  // pass 1: max
  float m = -1e30f;
  for (int j = tid; j < n; j += 256) m = fmaxf(m, srow[j]);
#pragma unroll
  for (int off = 32; off > 0; off >>= 1) m = fmaxf(m, __shfl_down(m, off, 64));
  if ((tid & 63) == 0) red[tid >> 6] = m;
  __syncthreads();
  if (tid == 0) red[4] = fmaxf(fmaxf(red[0], red[1]), fmaxf(red[2], red[3]));
  __syncthreads();
  float ms = red[4] * scale;

  // pass 2: sum of exp
  float s = 0.f;
  for (int j = tid; j < n; j += 256) s += __expf(srow[j] * scale - ms);
#pragma unroll
  for (int off = 32; off > 0; off >>= 1) s += __shfl_down(s, off, 64);
  if ((tid & 63) == 0) red[tid >> 6] = s;
  __syncthreads();
  if (tid == 0) red[5] = red[0] + red[1] + red[2] + red[3];
  __syncthreads();
  float inv = 1.f / red[5];

  // pass 3: write P (zeros above diagonal)
  for (int j = tid; j < n; j += 256)
    prow[j] = f2bf(__expf(srow[j] * scale - ms) * inv);
  for (int j = n + tid; j < S_LEN; j += 256)
    prow[j] = 0;
}

// ---------------- launch ----------------
extern "C" void kernel_launch(void* const* d_in, const int* in_sizes, int n_in,
                              void* d_out, int out_size, void* d_ws, size_t ws_size,
                              hipStream_t stream) {
  const float* x  = (const float*)d_in[0];
  const float* Wq = (const float*)d_in[1];
  const float* Wk = (const float*)d_in[2];
  const float* Wv = (const float*)d_in[3];
  float* out = (float*)d_out;

  // workspace layout (bytes)
  char* ws = (char*)d_ws;
  u16*   xb  = (u16*)(ws);                    // 8192x1024 bf16         : 16,777,216
  u16*   wtb = (u16*)(ws + 16777216);         // 3 x 1024x1024 bf16 (W^T): 6,291,456
  u16*   Qb  = (u16*)(ws + 23068672);         // [4][2048][1024] bf16   : 16,777,216
  u16*   Kb  = (u16*)(ws + 39845888);         // [4][2048][1024] bf16   : 16,777,216
  u16*   Vtb = (u16*)(ws + 56623104);         // [4][1024][2048] bf16   : 16,777,216
  float* sc  = (float*)(ws + 73400320);       // [4][2048][2048] f32    : 67,108,864
  u16*   P   = (u16*)(ws + 140509184);        // [4][2048][2048] bf16   : 33,554,432
  // total: 174,063,616 bytes

  long nx = (long)NBATCH * S_LEN * DMODEL;
  convert_x_kernel<<<2048, 256, 0, stream>>>(x, xb, nx);

  dim3 tb(32, 8);
  transpose_w_kernel<<<dim3(32, 32), tb, 0, stream>>>(Wq, wtb);
  transpose_w_kernel<<<dim3(32, 32), tb, 0, stream>>>(Wk, wtb + 1024 * 1024);
  transpose_w_kernel<<<dim3(32, 32), tb, 0, stream>>>(Wv, wtb + 2 * 1024 * 1024);

  // projections: M=8192 (B*S), N=1024, K=1024.  Q,K row-major bf16; V written transposed.
  gemm_nt<1, 0><<<dim3(64, 8, 1), 256, 0, stream>>>(xb, wtb,               Qb,  DMODEL, DMODEL, DMODEL, DMODEL, 0, 0, 0);
  gemm_nt<1, 0><<<dim3(64, 8, 1), 256, 0, stream>>>(xb, wtb + 1024 * 1024, Kb,  DMODEL, DMODEL, DMODEL, DMODEL, 0, 0, 0);
  gemm_nt<2, 0><<<dim3(64, 8, 1), 256, 0, stream>>>(xb, wtb + 2 * 1024 * 1024, Vtb, DMODEL, DMODEL, S_LEN, DMODEL, 0, 0, 0);

  // scores (unscaled): per batch, S = Q * K^T, causal tile skip, f32 out
  gemm_nt<0, 1><<<dim3(16, 16, 4), 256, 0, stream>>>(Qb, Kb, sc, DMODEL, DMODEL, S_LEN, DMODEL,
                                                     (long)S_LEN * DMODEL, (long)S_LEN * DMODEL,
                                                     (long)S_LEN * S_LEN);

  // softmax rows (applies 1/sqrt(dk) scale, causal mask, writes bf16 P with zeros)
  softmax_row_kernel<<<dim3(S_LEN, NBATCH), 256, 0, stream>>>(sc, P);

  // O = P * V : A = P [2048][2048] bf16, B = Vt [1024][2048] bf16, C = out f32, causal K-limit
  gemm_nt<0, 2><<<dim3(16, 8, 4), 256, 0, stream>>>(P, Vtb, out, S_LEN, S_LEN, DMODEL, S_LEN,
                                                    (long)S_LEN * S_LEN, (long)DMODEL * S_LEN,
                                                    (long)S_LEN * DMODEL);
}

// Round 3
// 219.384 us; speedup vs baseline: 1.1305x; 1.1305x over previous
//
#include <hip/hip_runtime.h>

#define S_LEN 2048
#define DMODEL 1024
#define NBATCH 4

typedef unsigned short u16;
typedef __bf16 bf16x8 __attribute__((ext_vector_type(8)));
typedef float f32x4 __attribute__((ext_vector_type(4)));

typedef __attribute__((address_space(3))) unsigned lds_u32;
typedef const __attribute__((address_space(1))) unsigned glb_u32;

__device__ __forceinline__ u16 f2bf(float f) {
  union { float f; unsigned u; } v;
  v.f = f;
  unsigned r = v.u + 0x7fffu + ((v.u >> 16) & 1u);
  return (u16)(r >> 16);
}

// ---------------- convert x: fp32 -> bf16, flat ----------------
__global__ void convert_x_kernel(const float* __restrict__ x, u16* __restrict__ xb, long n) {
  long i = ((long)blockIdx.x * blockDim.x + threadIdx.x) * 4;
  long stride = (long)gridDim.x * blockDim.x * 4;
  for (; i < n; i += stride) {
    float4 v = *reinterpret_cast<const float4*>(x + i);
    ushort4 o;
    o.x = f2bf(v.x); o.y = f2bf(v.y); o.z = f2bf(v.z); o.w = f2bf(v.w);
    *reinterpret_cast<ushort4*>(xb + i) = o;
  }
}

// ---------------- transpose-convert W: Wt[n][k] = bf16(W[k][n]), 1024x1024 ----------------
__global__ void transpose_w_kernel(const float* __restrict__ W, u16* __restrict__ Wt) {
  __shared__ float tile[32][33];
  int tx = threadIdx.x, ty = threadIdx.y;
  int k0 = blockIdx.x * 32, n0 = blockIdx.y * 32;
#pragma unroll
  for (int i = 0; i < 32; i += 8)
    tile[ty + i][tx] = W[(long)(k0 + ty + i) * DMODEL + n0 + tx];
  __syncthreads();
#pragma unroll
  for (int i = 0; i < 32; i += 8)
    Wt[(long)(n0 + ty + i) * DMODEL + k0 + tx] = f2bf(tile[tx][ty + i]);
}

// ================= 256x256 8-phase NT GEMM =================
// C[M][N] = A[M][K] * B[N][K]^T. BM=BN=256, BK=64, 512 threads = 8 waves (2M x 4N).
// Each wave: 2x2 quadrant chunks (qm,qn), each 4Mfrag x 2Nfrag of 16x16x32 MFMA.
// LDS 128 KiB: buf{0,1} x (A 32KB | B 32KB), 1024B subtiles [16 rows][32 cols] bf16,
// st_16x32 swizzle inside each subtile (inner ^= ((inner>>9)&1)<<5).
// Staged linear via global_load_lds(16B) from inverse-swizzled global source; reads
// apply the same involution (frag_off). Counted vmcnt(6) at phases j=0 and j=3.
// Stage schedule per group g: j0:A-half1(g+1)->buf^1, j1:B-half1(g+1)->buf^1,
//                             j2:A-half0(g+2)->buf,   j3:B-half0(g+2)->buf.
// CMODE: 0 = f32 row-major (+bz*sCz); 3 = fused QKV epilogue (Q/K row-major bf16, V transposed)
// CAUSAL: 0 none; 1 skip bn>bm; 2 Keff=(bm+1)*256

#define STG(SRCP, LD, ISB, H, T, BUFB) do { \
    const u16* _s = (SRCP) + (long)(H) * 128 * (LD) + (T) * 64; \
    char* _d = lds + (BUFB) * 65536 + ((ISB) ? 32768 : 0) + ((H) * 8 + w) * 2048; \
    __builtin_amdgcn_global_load_lds((glb_u32*)_s, (lds_u32*)_d, 16, 0, 0); \
    __builtin_amdgcn_global_load_lds((glb_u32*)(_s + 32), (lds_u32*)(_d + 1024), 16, 0, 0); \
  } while (0)

#define PHASE(QM, QN, BUFC, STAGE_STMT, DO_VM) do { \
    const char* _Al = lds + (BUFC) * 65536; \
    const char* _Bl = _Al + 32768; \
    bf16x8 _af[4][2], _bf[2][2]; \
    _Pragma("unroll") \
    for (int _i = 0; _i < 4; ++_i) { \
      int _mp = (QM) * 8 + wm * 4 + _i; \
      _af[_i][0] = *(const bf16x8*)(_Al + (_mp * 2 + 0) * 1024 + frag_off); \
      _af[_i][1] = *(const bf16x8*)(_Al + (_mp * 2 + 1) * 1024 + frag_off); \
    } \
    _Pragma("unroll") \
    for (int _j = 0; _j < 2; ++_j) { \
      int _np = (QN) * 8 + wn * 2 + _j; \
      _bf[_j][0] = *(const bf16x8*)(_Bl + (_np * 2 + 0) * 1024 + frag_off); \
      _bf[_j][1] = *(const bf16x8*)(_Bl + (_np * 2 + 1) * 1024 + frag_off); \
    } \
    STAGE_STMT; \
    __builtin_amdgcn_s_barrier(); \
    asm volatile("s_waitcnt lgkmcnt(0)" ::: "memory"); \
    __builtin_amdgcn_sched_barrier(0); \
    __builtin_amdgcn_s_setprio(1); \
    _Pragma("unroll") \
    for (int _i = 0; _i < 4; ++_i) \
      _Pragma("unroll") \
      for (int _j = 0; _j < 2; ++_j) { \
        acc[QM][QN][_i][_j] = __builtin_amdgcn_mfma_f32_16x16x32_bf16(_af[_i][0], _bf[_j][0], acc[QM][QN][_i][_j], 0, 0, 0); \
        acc[QM][QN][_i][_j] = __builtin_amdgcn_mfma_f32_16x16x32_bf16(_af[_i][1], _bf[_j][1], acc[QM][QN][_i][_j], 0, 0, 0); \
      } \
    __builtin_amdgcn_s_setprio(0); \
    if (DO_VM) asm volatile("s_waitcnt vmcnt(6)" ::: "memory"); \
    __builtin_amdgcn_s_barrier(); \
  } while (0)

template<int CMODE, int CAUSAL>
__global__ __launch_bounds__(512, 2) void gemm256(
    const u16* __restrict__ A, const u16* __restrict__ B, void* __restrict__ Cptr,
    int lda, int ldb, int ldc, int Kdim,
    long sAz, long sBz, long sCz)
{
  int bm = blockIdx.x, bn = blockIdx.y, bz = blockIdx.z;
  if (CAUSAL == 1 && bn > bm) return;
  int Keff = Kdim;
  if (CAUSAL == 2) { int lim = (bm + 1) * 256; if (lim < Keff) Keff = lim; }
  int NT = Keff >> 6;   // number of K-tiles (BK=64); always even and >= 4 here

  const u16* Ab = A + (long)bz * sAz + (long)bm * 256 * lda;
  const u16* Bb = B + (long)bz * sBz + (long)bn * 256 * ldb;

  __shared__ char lds[131072];

  int tid = threadIdx.x;
  int lane = tid & 63, w = tid >> 6;
  int wm = w >> 2, wn = w & 3;
  int l15 = lane & 15, lhi = lane >> 4;
  // fragment read offset within a 1024B subtile (st_16x32 swizzled)
  int frag_off = (l15 * 64 + lhi * 16) ^ (((lane >> 3) & 1) << 5);

  // staging: lane's linear 16B chunk at l*16 corresponds to logical inner (l ^ (l>=32?2:0))*16
  int le = lane ^ ((lane >> 5) << 1);
  int lr = le >> 2;          // row within 16-row subtile
  int kb = (le & 3) * 8;     // k-element offset within 32-col subtile

  const u16* Asrc = Ab + (long)(w * 16 + lr) * lda + kb;
  const u16* Bsrc = Bb + (long)(w * 16 + lr) * ldb + kb;

  f32x4 acc[2][2][4][2];
#pragma unroll
  for (int a = 0; a < 2; ++a)
#pragma unroll
    for (int b = 0; b < 2; ++b)
#pragma unroll
      for (int c = 0; c < 4; ++c)
#pragma unroll
        for (int d = 0; d < 2; ++d)
          acc[a][b][c][d] = (f32x4){0.f, 0.f, 0.f, 0.f};

  // prologue: tile0 all 4 halves, tile1 first 2 halves; wait so tile0 is resident
  STG(Asrc, lda, 0, 0, 0, 0); STG(Bsrc, ldb, 1, 0, 0, 0);
  STG(Asrc, lda, 0, 1, 0, 0); STG(Bsrc, ldb, 1, 1, 0, 0);
  STG(Asrc, lda, 0, 0, 1, 1); STG(Bsrc, ldb, 1, 0, 1, 1);
  asm volatile("s_waitcnt vmcnt(6)" ::: "memory");
  __builtin_amdgcn_s_barrier();

  for (int g = 0; g < NT; ++g) {
    int buf = g & 1;
    int t1 = g + 1; if (t1 >= NT) t1 -= NT;   // wrapped prefetch targets stay in-bounds;
    int t2 = g + 2; if (t2 >= NT) t2 -= NT;   // wrapped data is never read
    PHASE(0, 0, buf, STG(Asrc, lda, 0, 1, t1, buf ^ 1), 1);
    PHASE(0, 1, buf, STG(Bsrc, ldb, 1, 1, t1, buf ^ 1), 0);
    PHASE(1, 0, buf, STG(Asrc, lda, 0, 0, t2, buf), 0);
    PHASE(1, 1, buf, STG(Bsrc, ldb, 1, 0, t2, buf), 1);
  }

  // epilogue: C/D frag mapping (verified r0/r1): row = base + lhi*4 + reg, col = base + l15
  int Mbase = bm * 256, Nbase = bn * 256;
#pragma unroll
  for (int qm = 0; qm < 2; ++qm)
#pragma unroll
    for (int qn = 0; qn < 2; ++qn)
#pragma unroll
      for (int i = 0; i < 4; ++i)
#pragma unroll
        for (int j = 0; j < 2; ++j) {
          int r0 = Mbase + qm * 128 + wm * 64 + i * 16 + lhi * 4;
          int col = Nbase + qn * 128 + wn * 32 + j * 16 + l15;
          f32x4 v = acc[qm][qn][i][j];
          if constexpr (CMODE == 0) {
            float* C = (float*)Cptr + (long)bz * sCz;
#pragma unroll
            for (int r = 0; r < 4; ++r)
              C[(long)(r0 + r) * ldc + col] = v[r];
          } else {
            // fused QKV projection epilogue: cols [0,1024)=Q, [1024,2048)=K row-major bf16;
            // cols [2048,3072)=V written transposed into Vt[b][e][s]
            if (col < 2048) {
              u16* dst = (u16*)Cptr + (col >= 1024 ? 8388608 : 0);
              int c = col & 1023;
#pragma unroll
              for (int r = 0; r < 4; ++r)
                dst[(long)(r0 + r) * 1024 + c] = f2bf(v[r]);
            } else {
              u16* Vt = (u16*)Cptr + 16777216;
              int e = col - 2048;
              int bb = r0 >> 11, s = r0 & 2047;
              ushort4 u;
              u.x = f2bf(v[0]); u.y = f2bf(v[1]); u.z = f2bf(v[2]); u.w = f2bf(v[3]);
              *reinterpret_cast<ushort4*>(Vt + ((long)bb * 1024 + e) * 2048 + s) = u;
            }
          }
        }
}

// ---------------- causal row softmax: scores(f32, unscaled) -> P(bf16, normalized) ----------------
__global__ __launch_bounds__(256) void softmax_row_kernel(const float* __restrict__ scores,
                                                          u16* __restrict__ P) {
  int q = blockIdx.x, b = blockIdx.y;
  const float* srow = scores + ((long)b * S_LEN + q) * S_LEN;
  u16* prow = P + ((long)b * S_LEN + q) * S_LEN;
  int n = q + 1;
  int tid = threadIdx.x;
  const float scale = 0.03125f; // 1/sqrt(1024)

  __shared__ float red[8];

  float m = -1e30f;
  for (int j = tid; j < n; j += 256) m = fmaxf(m, srow[j]);
#pragma unroll
  for (int off = 32; off > 0; off >>= 1) m = fmaxf(m, __shfl_down(m, off, 64));
  if ((tid & 63) == 0) red[tid >> 6] = m;
  __syncthreads();
  if (tid == 0) red[4] = fmaxf(fmaxf(red[0], red[1]), fmaxf(red[2], red[3]));
  __syncthreads();
  float ms = red[4] * scale;

  float s = 0.f;
  for (int j = tid; j < n; j += 256) s += __expf(srow[j] * scale - ms);
#pragma unroll
  for (int off = 32; off > 0; off >>= 1) s += __shfl_down(s, off, 64);
  if ((tid & 63) == 0) red[tid >> 6] = s;
  __syncthreads();
  if (tid == 0) red[5] = red[0] + red[1] + red[2] + red[3];
  __syncthreads();
  float inv = 1.f / red[5];

  for (int j = tid; j < n; j += 256)
    prow[j] = f2bf(__expf(srow[j] * scale - ms) * inv);
  for (int j = n + tid; j < S_LEN; j += 256)
    prow[j] = 0;
}

// ---------------- launch ----------------
extern "C" void kernel_launch(void* const* d_in, const int* in_sizes, int n_in,
                              void* d_out, int out_size, void* d_ws, size_t ws_size,
                              hipStream_t stream) {
  const float* x  = (const float*)d_in[0];
  const float* Wq = (const float*)d_in[1];
  const float* Wk = (const float*)d_in[2];
  const float* Wv = (const float*)d_in[3];
  float* out = (float*)d_out;

  // workspace layout (bytes)
  char* ws = (char*)d_ws;
  u16*   xb  = (u16*)(ws);                    // [8192][1024] bf16       : 16,777,216
  u16*   wtb = (u16*)(ws + 16777216);         // [3072][1024] bf16 (W^T) :  6,291,456
  u16*   Qb  = (u16*)(ws + 23068672);         // [4][2048][1024] bf16    : 16,777,216
  u16*   Kb  = (u16*)(ws + 39845888);         // [4][2048][1024] bf16    : 16,777,216 (= Qb + 8M elems)
  u16*   Vtb = (u16*)(ws + 56623104);         // [4][1024][2048] bf16    : 16,777,216 (= Qb + 16M elems)
  float* sc  = (float*)(ws + 73400320);       // [4][2048][2048] f32     : 67,108,864
  u16*   P   = (u16*)(ws + 140509184);        // [4][2048][2048] bf16    : 33,554,432

  long nx = (long)NBATCH * S_LEN * DMODEL;
  convert_x_kernel<<<2048, 256, 0, stream>>>(x, xb, nx);

  dim3 tb(32, 8);
  transpose_w_kernel<<<dim3(32, 32), tb, 0, stream>>>(Wq, wtb);
  transpose_w_kernel<<<dim3(32, 32), tb, 0, stream>>>(Wk, wtb + 1024 * 1024);
  transpose_w_kernel<<<dim3(32, 32), tb, 0, stream>>>(Wv, wtb + 2 * 1024 * 1024);

  // fused QKV projection: M=8192, N=3072 (Q|K|V), K=1024
  gemm256<3, 0><<<dim3(32, 12, 1), 512, 0, stream>>>(
      xb, wtb, Qb, DMODEL, DMODEL, 0, DMODEL, 0, 0, 0);

  // scores (unscaled): per batch S = Q*K^T, causal block skip, f32 out
  gemm256<0, 1><<<dim3(8, 8, 4), 512, 0, stream>>>(
      Qb, Kb, sc, DMODEL, DMODEL, S_LEN, DMODEL,
      (long)S_LEN * DMODEL, (long)S_LEN * DMODEL, (long)S_LEN * S_LEN);

  softmax_row_kernel<<<dim3(S_LEN, NBATCH), 256, 0, stream>>>(sc, P);

  // O = P * V : A = P [2048][2048] bf16, B = Vt [1024][2048] bf16, K-limited
  gemm256<0, 2><<<dim3(8, 4, 4), 512, 0, stream>>>(
      P, Vtb, out, S_LEN, S_LEN, DMODEL, S_LEN,
      (long)S_LEN * S_LEN, (long)DMODEL * S_LEN, (long)S_LEN * DMODEL);
}

// Round 4
// 185.814 us; speedup vs baseline: 1.3348x; 1.1807x over previous
//
#include <hip/hip_runtime.h>

#define S_LEN 2048
#define DMODEL 1024
#define NBATCH 4

typedef unsigned short u16;
typedef __bf16 bf16x8 __attribute__((ext_vector_type(8)));
typedef float f32x4 __attribute__((ext_vector_type(4)));

typedef __attribute__((address_space(3))) unsigned lds_u32;
typedef const __attribute__((address_space(1))) unsigned glb_u32;

__device__ __forceinline__ u16 f2bf(float f) {
  union { float f; unsigned u; } v;
  v.f = f;
  unsigned r = v.u + 0x7fffu + ((v.u >> 16) & 1u);
  return (u16)(r >> 16);
}

__device__ __forceinline__ float bf2f(u16 h) {
  union { unsigned u; float f; } v;
  v.u = ((unsigned)h) << 16;
  return v.f;
}

// ---------------- convert x: fp32 -> bf16, flat ----------------
__global__ void convert_x_kernel(const float* __restrict__ x, u16* __restrict__ xb, long n) {
  long i = ((long)blockIdx.x * blockDim.x + threadIdx.x) * 4;
  long stride = (long)gridDim.x * blockDim.x * 4;
  for (; i < n; i += stride) {
    float4 v = *reinterpret_cast<const float4*>(x + i);
    ushort4 o;
    o.x = f2bf(v.x); o.y = f2bf(v.y); o.z = f2bf(v.z); o.w = f2bf(v.w);
    *reinterpret_cast<ushort4*>(xb + i) = o;
  }
}

// ---------------- transpose-convert W: Wt[n][k] = bf16(W[k][n]), 1024x1024 ----------------
__global__ void transpose_w_kernel(const float* __restrict__ W, u16* __restrict__ Wt) {
  __shared__ float tile[32][33];
  int tx = threadIdx.x, ty = threadIdx.y;
  int k0 = blockIdx.x * 32, n0 = blockIdx.y * 32;
#pragma unroll
  for (int i = 0; i < 32; i += 8)
    tile[ty + i][tx] = W[(long)(k0 + ty + i) * DMODEL + n0 + tx];
  __syncthreads();
#pragma unroll
  for (int i = 0; i < 32; i += 8)
    Wt[(long)(n0 + ty + i) * DMODEL + k0 + tx] = f2bf(tile[tx][ty + i]);
}

// ================= 256x256 NT GEMM, 2-phase/K-tile with A/B frag reuse =================
// C[M][N] = A[M][K] * B[N][K]^T. BM=BN=256, BK=64, 512 threads = 8 waves (2M x 4N).
// LDS 128 KiB: buf{0,1} x (A 32KB | B 32KB), 1024B subtiles [16r][32c] bf16, st_16x32
// swizzle (inner ^= ((inner>>9)&1)<<5), staged linear via global_load_lds from
// inverse-swizzled global source, read back with the same involution (frag_off).
// Per K-tile g: phase alpha reads B(qn0)+B(qn1)+A(qm0) frags [16 b128], stages
// halves-1 of tile g+1 -> buf^1, 32 MFMA (qm0); phase beta reads A(qm1) [8 b128,
// B frags held in regs], stages halves-0 of tile g+2 -> buf, 32 MFMA (qm1),
// vmcnt(4). FIFO: 4 loads/phase, outstanding 4..12, tile g+1 resident before its
// alpha. Write-after-read safe: each phase's ds_reads drain at its own lgkmcnt(0)
// before its closing barrier, so later STGs into that slot cannot race.
// CMODE: 0 = f32 row-major; 1 = bf16 row-major; 3 = fused QKV epilogue
// CAUSAL: 0 none; 1 skip bn>bm; 2 Keff=(bm+1)*256

#define STG(SRCP, LD, ISB, H, T, BUFB) do { \
    const u16* _s = (SRCP) + (long)(H) * 128 * (LD) + (T) * 64; \
    char* _d = lds + (BUFB) * 65536 + ((ISB) ? 32768 : 0) + ((H) * 8 + w) * 2048; \
    __builtin_amdgcn_global_load_lds((glb_u32*)_s, (lds_u32*)_d, 16, 0, 0); \
    __builtin_amdgcn_global_load_lds((glb_u32*)(_s + 32), (lds_u32*)(_d + 1024), 16, 0, 0); \
  } while (0)

#define READ_B() do { \
    _Pragma("unroll") \
    for (int _q = 0; _q < 2; ++_q) \
      _Pragma("unroll") \
      for (int _j = 0; _j < 2; ++_j) { \
        int _np = _q * 8 + wn * 2 + _j; \
        bfr[_q][_j][0] = *(const bf16x8*)(_Bl + (_np * 2 + 0) * 1024 + frag_off); \
        bfr[_q][_j][1] = *(const bf16x8*)(_Bl + (_np * 2 + 1) * 1024 + frag_off); \
      } \
  } while (0)

#define READ_A(QM) do { \
    _Pragma("unroll") \
    for (int _i = 0; _i < 4; ++_i) { \
      int _mp = (QM) * 8 + wm * 4 + _i; \
      af[_i][0] = *(const bf16x8*)(_Al + (_mp * 2 + 0) * 1024 + frag_off); \
      af[_i][1] = *(const bf16x8*)(_Al + (_mp * 2 + 1) * 1024 + frag_off); \
    } \
  } while (0)

#define MFMA32(QM) do { \
    _Pragma("unroll") \
    for (int _i = 0; _i < 4; ++_i) \
      _Pragma("unroll") \
      for (int _q = 0; _q < 2; ++_q) \
        _Pragma("unroll") \
        for (int _j = 0; _j < 2; ++_j) { \
          acc[QM][_q][_i][_j] = __builtin_amdgcn_mfma_f32_16x16x32_bf16(af[_i][0], bfr[_q][_j][0], acc[QM][_q][_i][_j], 0, 0, 0); \
          acc[QM][_q][_i][_j] = __builtin_amdgcn_mfma_f32_16x16x32_bf16(af[_i][1], bfr[_q][_j][1], acc[QM][_q][_i][_j], 0, 0, 0); \
        } \
  } while (0)

template<int CMODE, int CAUSAL>
__global__ __launch_bounds__(512, 2) void gemm256(
    const u16* __restrict__ A, const u16* __restrict__ B, void* __restrict__ Cptr,
    int lda, int ldb, int ldc, int Kdim,
    long sAz, long sBz, long sCz)
{
  int bm = blockIdx.x, bn = blockIdx.y, bz = blockIdx.z;
  if (CAUSAL == 1 && bn > bm) return;
  int Keff = Kdim;
  if (CAUSAL == 2) { int lim = (bm + 1) * 256; if (lim < Keff) Keff = lim; }
  int NT = Keff >> 6;   // K-tiles (BK=64); >= 4 in all our launches

  const u16* Ab = A + (long)bz * sAz + (long)bm * 256 * lda;
  const u16* Bb = B + (long)bz * sBz + (long)bn * 256 * ldb;

  __shared__ char lds[131072];

  int tid = threadIdx.x;
  int lane = tid & 63, w = tid >> 6;
  int wm = w >> 2, wn = w & 3;
  int l15 = lane & 15, lhi = lane >> 4;
  int frag_off = (l15 * 64 + lhi * 16) ^ (((lane >> 3) & 1) << 5);

  // staging source pre-swizzle: lane's linear 16B LDS chunk <- logical chunk (lane ^ hi-bit-pair)
  int le = lane ^ ((lane >> 5) << 1);
  int lr = le >> 2;
  int kb = (le & 3) * 8;

  const u16* Asrc = Ab + (long)(w * 16 + lr) * lda + kb;
  const u16* Bsrc = Bb + (long)(w * 16 + lr) * ldb + kb;

  f32x4 acc[2][2][4][2];
#pragma unroll
  for (int a = 0; a < 2; ++a)
#pragma unroll
    for (int b = 0; b < 2; ++b)
#pragma unroll
      for (int c = 0; c < 4; ++c)
#pragma unroll
        for (int d = 0; d < 2; ++d)
          acc[a][b][c][d] = (f32x4){0.f, 0.f, 0.f, 0.f};

  // prologue: tile0 fully (8 loads), tile1 halves-0 (4 loads); drain tile0 (12-8=vmcnt 4)
  STG(Asrc, lda, 0, 0, 0, 0); STG(Bsrc, ldb, 1, 0, 0, 0);
  STG(Asrc, lda, 0, 1, 0, 0); STG(Bsrc, ldb, 1, 1, 0, 0);
  STG(Asrc, lda, 0, 0, 1, 1); STG(Bsrc, ldb, 1, 0, 1, 1);
  asm volatile("s_waitcnt vmcnt(4)" ::: "memory");
  __builtin_amdgcn_s_barrier();

  for (int g = 0; g < NT; ++g) {
    int buf = g & 1;
    int t1 = g + 1; if (t1 >= NT) t1 -= NT;   // wrapped prefetch stays in-bounds;
    int t2 = g + 2; if (t2 >= NT) t2 -= NT;   // wrapped data never read
    const char* _Al = lds + buf * 65536;
    const char* _Bl = _Al + 32768;
    bf16x8 af[4][2], bfr[2][2][2];

    // ---- phase alpha: qm=0 ----
    READ_B();
    READ_A(0);
    STG(Asrc, lda, 0, 1, t1, buf ^ 1);
    STG(Bsrc, ldb, 1, 1, t1, buf ^ 1);
    __builtin_amdgcn_s_barrier();
    asm volatile("s_waitcnt lgkmcnt(0)" ::: "memory");
    __builtin_amdgcn_sched_barrier(0);
    __builtin_amdgcn_s_setprio(1);
    MFMA32(0);
    __builtin_amdgcn_s_setprio(0);
    __builtin_amdgcn_s_barrier();

    // ---- phase beta: qm=1 (B frags reused) ----
    READ_A(1);
    STG(Asrc, lda, 0, 0, t2, buf);
    STG(Bsrc, ldb, 1, 0, t2, buf);
    __builtin_amdgcn_s_barrier();
    asm volatile("s_waitcnt lgkmcnt(0)" ::: "memory");
    __builtin_amdgcn_sched_barrier(0);
    __builtin_amdgcn_s_setprio(1);
    MFMA32(1);
    __builtin_amdgcn_s_setprio(0);
    asm volatile("s_waitcnt vmcnt(4)" ::: "memory");
    __builtin_amdgcn_s_barrier();
  }

  // epilogue: C/D frag mapping: row = base + lhi*4 + reg, col = base + l15
  int Mbase = bm * 256, Nbase = bn * 256;
#pragma unroll
  for (int qm = 0; qm < 2; ++qm)
#pragma unroll
    for (int qn = 0; qn < 2; ++qn)
#pragma unroll
      for (int i = 0; i < 4; ++i)
#pragma unroll
        for (int j = 0; j < 2; ++j) {
          int r0 = Mbase + qm * 128 + wm * 64 + i * 16 + lhi * 4;
          int col = Nbase + qn * 128 + wn * 32 + j * 16 + l15;
          f32x4 v = acc[qm][qn][i][j];
          if constexpr (CMODE == 0) {
            float* C = (float*)Cptr + (long)bz * sCz;
#pragma unroll
            for (int r = 0; r < 4; ++r)
              C[(long)(r0 + r) * ldc + col] = v[r];
          } else if constexpr (CMODE == 1) {
            u16* C = (u16*)Cptr + (long)bz * sCz;
#pragma unroll
            for (int r = 0; r < 4; ++r)
              C[(long)(r0 + r) * ldc + col] = f2bf(v[r]);
          } else {
            // fused QKV: cols [0,1024)=Q, [1024,2048)=K row-major bf16; [2048,3072)=V -> Vt[b][e][s]
            if (col < 2048) {
              u16* dst = (u16*)Cptr + (col >= 1024 ? 8388608 : 0);
              int c = col & 1023;
#pragma unroll
              for (int r = 0; r < 4; ++r)
                dst[(long)(r0 + r) * 1024 + c] = f2bf(v[r]);
            } else {
              u16* Vt = (u16*)Cptr + 16777216;
              int e = col - 2048;
              int bb = r0 >> 11, s = r0 & 2047;
              ushort4 u;
              u.x = f2bf(v[0]); u.y = f2bf(v[1]); u.z = f2bf(v[2]); u.w = f2bf(v[3]);
              *reinterpret_cast<ushort4*>(Vt + ((long)bb * 1024 + e) * 2048 + s) = u;
            }
          }
        }
}

// ---------------- one-pass causal row softmax: sc(bf16, unscaled) -> P(bf16) ----------------
// 256 threads/row, 8 elems/thread held in registers; single read, single write.
// Zero-fills only [n, 256-aligned K-limit) -- PV never reads beyond (q>>8+1)*256.
__global__ __launch_bounds__(256) void softmax1p(const u16* __restrict__ sc,
                                                 u16* __restrict__ P) {
  int q = blockIdx.x, b = blockIdx.y;
  const u16* srow = sc + ((long)b * S_LEN + q) * S_LEN;
  u16* prow = P + ((long)b * S_LEN + q) * S_LEN;
  int n = q + 1;
  int nz = ((q >> 8) + 1) << 8;   // zero-fill bound (256-aligned)
  int tid = threadIdx.x;
  int j0 = tid * 8;
  const float scale = 0.03125f;   // 1/sqrt(1024)

  __shared__ float red[8];

  float vs[8];
#pragma unroll
  for (int e = 0; e < 8; ++e) vs[e] = -1e30f;
  if (j0 < n) {
    ushort4 a = *reinterpret_cast<const ushort4*>(srow + j0);
    ushort4 c = *reinterpret_cast<const ushort4*>(srow + j0 + 4);
    vs[0] = bf2f(a.x) * scale; vs[1] = bf2f(a.y) * scale;
    vs[2] = bf2f(a.z) * scale; vs[3] = bf2f(a.w) * scale;
    vs[4] = bf2f(c.x) * scale; vs[5] = bf2f(c.y) * scale;
    vs[6] = bf2f(c.z) * scale; vs[7] = bf2f(c.w) * scale;
#pragma unroll
    for (int e = 0; e < 8; ++e)
      if (j0 + e >= n) vs[e] = -1e30f;
  }

  // max reduce
  float m = -1e30f;
#pragma unroll
  for (int e = 0; e < 8; ++e) m = fmaxf(m, vs[e]);
#pragma unroll
  for (int off = 32; off > 0; off >>= 1) m = fmaxf(m, __shfl_xor(m, off, 64));
  if ((tid & 63) == 0) red[tid >> 6] = m;
  __syncthreads();
  float ms = fmaxf(fmaxf(red[0], red[1]), fmaxf(red[2], red[3]));

  // sum of exp
  float p[8];
  float s = 0.f;
#pragma unroll
  for (int e = 0; e < 8; ++e) { p[e] = __expf(vs[e] - ms); s += (j0 + e < n) ? p[e] : 0.f; }
#pragma unroll
  for (int off = 32; off > 0; off >>= 1) s += __shfl_xor(s, off, 64);
  __syncthreads();
  if ((tid & 63) == 0) red[4 + (tid >> 6)] = s;
  __syncthreads();
  float inv = 1.f / (red[4] + red[5] + red[6] + red[7]);

  if (j0 < nz) {
    ushort4 o0, o1;
    o0.x = (j0 + 0 < n) ? f2bf(p[0] * inv) : (u16)0;
    o0.y = (j0 + 1 < n) ? f2bf(p[1] * inv) : (u16)0;
    o0.z = (j0 + 2 < n) ? f2bf(p[2] * inv) : (u16)0;
    o0.w = (j0 + 3 < n) ? f2bf(p[3] * inv) : (u16)0;
    o1.x = (j0 + 4 < n) ? f2bf(p[4] * inv) : (u16)0;
    o1.y = (j0 + 5 < n) ? f2bf(p[5] * inv) : (u16)0;
    o1.z = (j0 + 6 < n) ? f2bf(p[6] * inv) : (u16)0;
    o1.w = (j0 + 7 < n) ? f2bf(p[7] * inv) : (u16)0;
    *reinterpret_cast<ushort4*>(prow + j0) = o0;
    *reinterpret_cast<ushort4*>(prow + j0 + 4) = o1;
  }
}

// ---------------- launch ----------------
extern "C" void kernel_launch(void* const* d_in, const int* in_sizes, int n_in,
                              void* d_out, int out_size, void* d_ws, size_t ws_size,
                              hipStream_t stream) {
  const float* x  = (const float*)d_in[0];
  const float* Wq = (const float*)d_in[1];
  const float* Wk = (const float*)d_in[2];
  const float* Wv = (const float*)d_in[3];
  float* out = (float*)d_out;

  // workspace layout (bytes)
  char* ws = (char*)d_ws;
  u16* xb  = (u16*)(ws);                    // [8192][1024] bf16        : 16,777,216
  u16* wtb = (u16*)(ws + 16777216);         // [3072][1024] bf16 (W^T)  :  6,291,456
  u16* Qb  = (u16*)(ws + 23068672);         // [4][2048][1024] bf16     : 16,777,216
  u16* Kb  = (u16*)(ws + 39845888);         // [4][2048][1024] bf16
  u16* Vtb = (u16*)(ws + 56623104);         // [4][1024][2048] bf16
  u16* scb = (u16*)(ws + 73400320);         // [4][2048][2048] bf16     : 33,554,432
  u16* P   = (u16*)(ws + 106954752);        // [4][2048][2048] bf16     : 33,554,432
  // total 140,509,184 bytes

  long nx = (long)NBATCH * S_LEN * DMODEL;
  convert_x_kernel<<<2048, 256, 0, stream>>>(x, xb, nx);

  dim3 tb(32, 8);
  transpose_w_kernel<<<dim3(32, 32), tb, 0, stream>>>(Wq, wtb);
  transpose_w_kernel<<<dim3(32, 32), tb, 0, stream>>>(Wk, wtb + 1024 * 1024);
  transpose_w_kernel<<<dim3(32, 32), tb, 0, stream>>>(Wv, wtb + 2 * 1024 * 1024);

  // fused QKV projection: M=8192, N=3072 (Q|K|V), K=1024
  gemm256<3, 0><<<dim3(32, 12, 1), 512, 0, stream>>>(
      xb, wtb, Qb, DMODEL, DMODEL, 0, DMODEL, 0, 0, 0);

  // scores (unscaled, bf16): per batch S = Q*K^T, causal block skip
  gemm256<1, 1><<<dim3(8, 8, 4), 512, 0, stream>>>(
      Qb, Kb, scb, DMODEL, DMODEL, S_LEN, DMODEL,
      (long)S_LEN * DMODEL, (long)S_LEN * DMODEL, (long)S_LEN * S_LEN);

  softmax1p<<<dim3(S_LEN, NBATCH), 256, 0, stream>>>(scb, P);

  // O = P * V : A = P [2048][2048] bf16, B = Vt [1024][2048] bf16, K-limited
  gemm256<0, 2><<<dim3(8, 4, 4), 512, 0, stream>>>(
      P, Vtb, out, S_LEN, S_LEN, DMODEL, S_LEN,
      (long)S_LEN * S_LEN, (long)DMODEL * S_LEN, (long)S_LEN * DMODEL);
}

// Round 5
// 185.664 us; speedup vs baseline: 1.3358x; 1.0008x over previous
//
#include <hip/hip_runtime.h>

#define S_LEN 2048
#define DMODEL 1024
#define NBATCH 4

typedef unsigned short u16;
typedef __bf16 bf16x8 __attribute__((ext_vector_type(8)));
typedef float f32x4 __attribute__((ext_vector_type(4)));

typedef __attribute__((address_space(3))) unsigned lds_u32;
typedef const __attribute__((address_space(1))) unsigned glb_u32;

__device__ __forceinline__ u16 f2bf(float f) {
  union { float f; unsigned u; } v;
  v.f = f;
  unsigned r = v.u + 0x7fffu + ((v.u >> 16) & 1u);
  return (u16)(r >> 16);
}

__device__ __forceinline__ float bf2f(u16 h) {
  union { unsigned u; float f; } v;
  v.u = ((unsigned)h) << 16;
  return v.f;
}

// ---------------- convert x: fp32 -> bf16, flat ----------------
__global__ void convert_x_kernel(const float* __restrict__ x, u16* __restrict__ xb, long n) {
  long i = ((long)blockIdx.x * blockDim.x + threadIdx.x) * 4;
  long stride = (long)gridDim.x * blockDim.x * 4;
  for (; i < n; i += stride) {
    float4 v = *reinterpret_cast<const float4*>(x + i);
    ushort4 o;
    o.x = f2bf(v.x); o.y = f2bf(v.y); o.z = f2bf(v.z); o.w = f2bf(v.w);
    *reinterpret_cast<ushort4*>(xb + i) = o;
  }
}

// ---------------- transpose-convert W: Wt[n][k] = bf16(W[k][n]), 1024x1024 ----------------
__global__ void transpose_w_kernel(const float* __restrict__ W, u16* __restrict__ Wt) {
  __shared__ float tile[32][33];
  int tx = threadIdx.x, ty = threadIdx.y;
  int k0 = blockIdx.x * 32, n0 = blockIdx.y * 32;
#pragma unroll
  for (int i = 0; i < 32; i += 8)
    tile[ty + i][tx] = W[(long)(k0 + ty + i) * DMODEL + n0 + tx];
  __syncthreads();
#pragma unroll
  for (int i = 0; i < 32; i += 8)
    Wt[(long)(n0 + ty + i) * DMODEL + k0 + tx] = f2bf(tile[tx][ty + i]);
}

// ================= 256x256 NT GEMM, 4-phase/K-tile (m201-style) =================
// C[M][N] = A[M][K] * B[N][K]^T. BM=BN=256, BK=64, 512 threads = 8 waves (2M x 4N).
// LDS 128 KiB: buf{0,1} x (A 32KB | B 32KB), 1024B subtiles [16r][32c] bf16, st_16x32
// swizzle, staged linear via global_load_lds from inverse-swizzled global source,
// read back with the same involution (frag_off). Per K-tile g, 4 phases, one
// C-quadrant (16 MFMA) each, quadrant order (m0n0),(m0n1),(m1n1),(m1n0):
//   p0: read A(m0)[8 b128]+B(n0)[4]; stage A-h1(g+1)->buf^1; bar; lgkm; 16 MFMA; bar
//   p1: read B(n1)[4];               stage B-h1(g+1)->buf^1; bar; lgkm; 16 MFMA; bar
//   p2: read A(m1)[8];               stage A-h0(g+2)->buf;   bar; lgkm; 16 MFMA; bar
//   p3: (no ds reads, b0 held)       stage B-h0(g+2)->buf;   bar; 16 MFMA; vmcnt(4); bar
// Per-thread load FIFO: enter tile with 4 outstanding (halves-0 of g+1), issue 8,
// vmcnt(4) at p3 drains exactly tile g+1's 8 loads -> tile g+1 fully resident.
// WAR-safety: every LDS region's readers drain at their phase's lgkmcnt(0), >=2
// barriers before any STG overwrites that region.
// CMODE: 0 = f32 row-major; 1 = bf16 row-major; 3 = fused QKV epilogue
// CAUSAL: 0 none; 1 skip bn>bm; 2 Keff=(bm+1)*256

#define STG(SRCP, LD, ISB, H, T, BUFB) do { \
    const u16* _s = (SRCP) + (long)(H) * 128 * (LD) + (T) * 64; \
    char* _d = lds + (BUFB) * 65536 + ((ISB) ? 32768 : 0) + ((H) * 8 + w) * 2048; \
    __builtin_amdgcn_global_load_lds((glb_u32*)_s, (lds_u32*)_d, 16, 0, 0); \
    __builtin_amdgcn_global_load_lds((glb_u32*)(_s + 32), (lds_u32*)(_d + 1024), 16, 0, 0); \
  } while (0)

#define READ_A(QM) do { \
    _Pragma("unroll") \
    for (int _i = 0; _i < 4; ++_i) { \
      int _mp = (QM) * 8 + wm * 4 + _i; \
      af[_i][0] = *(const bf16x8*)(_Al + (_mp * 2 + 0) * 1024 + frag_off); \
      af[_i][1] = *(const bf16x8*)(_Al + (_mp * 2 + 1) * 1024 + frag_off); \
    } \
  } while (0)

#define READ_BQ(DST, QN) do { \
    _Pragma("unroll") \
    for (int _j = 0; _j < 2; ++_j) { \
      int _np = (QN) * 8 + wn * 2 + _j; \
      DST[_j][0] = *(const bf16x8*)(_Bl + (_np * 2 + 0) * 1024 + frag_off); \
      DST[_j][1] = *(const bf16x8*)(_Bl + (_np * 2 + 1) * 1024 + frag_off); \
    } \
  } while (0)

#define MFMA16(QM, QN, BREG) do { \
    _Pragma("unroll") \
    for (int _i = 0; _i < 4; ++_i) \
      _Pragma("unroll") \
      for (int _j = 0; _j < 2; ++_j) { \
        acc[QM][QN][_i][_j] = __builtin_amdgcn_mfma_f32_16x16x32_bf16(af[_i][0], BREG[_j][0], acc[QM][QN][_i][_j], 0, 0, 0); \
        acc[QM][QN][_i][_j] = __builtin_amdgcn_mfma_f32_16x16x32_bf16(af[_i][1], BREG[_j][1], acc[QM][QN][_i][_j], 0, 0, 0); \
      } \
  } while (0)

template<int CMODE, int CAUSAL>
__global__ __launch_bounds__(512, 2) void gemm256(
    const u16* __restrict__ A, const u16* __restrict__ B, void* __restrict__ Cptr,
    int lda, int ldb, int ldc, int Kdim,
    long sAz, long sBz, long sCz)
{
  int bm = blockIdx.x, bn = blockIdx.y, bz = blockIdx.z;
  if (CAUSAL == 1 && bn > bm) return;
  int Keff = Kdim;
  if (CAUSAL == 2) { int lim = (bm + 1) * 256; if (lim < Keff) Keff = lim; }
  int NT = Keff >> 6;   // K-tiles (BK=64); >= 4 in all our launches

  const u16* Ab = A + (long)bz * sAz + (long)bm * 256 * lda;
  const u16* Bb = B + (long)bz * sBz + (long)bn * 256 * ldb;

  __shared__ char lds[131072];

  int tid = threadIdx.x;
  int lane = tid & 63, w = tid >> 6;
  int wm = w >> 2, wn = w & 3;
  int l15 = lane & 15, lhi = lane >> 4;
  int frag_off = (l15 * 64 + lhi * 16) ^ (((lane >> 3) & 1) << 5);

  // staging source pre-swizzle: lane's linear 16B LDS chunk <- logical chunk (lane ^ hi-bit-pair)
  int le = lane ^ ((lane >> 5) << 1);
  int lr = le >> 2;
  int kb = (le & 3) * 8;

  const u16* Asrc = Ab + (long)(w * 16 + lr) * lda + kb;
  const u16* Bsrc = Bb + (long)(w * 16 + lr) * ldb + kb;

  f32x4 acc[2][2][4][2];
#pragma unroll
  for (int a = 0; a < 2; ++a)
#pragma unroll
    for (int b = 0; b < 2; ++b)
#pragma unroll
      for (int c = 0; c < 4; ++c)
#pragma unroll
        for (int d = 0; d < 2; ++d)
          acc[a][b][c][d] = (f32x4){0.f, 0.f, 0.f, 0.f};

  // prologue: tile0 (A-h0,B-h0,A-h1,B-h1) + tile1 halves-0; vmcnt(4) -> tile0 resident,
  // 4 outstanding = halves-0(1) = steady-state invariant.
  STG(Asrc, lda, 0, 0, 0, 0); STG(Bsrc, ldb, 1, 0, 0, 0);
  STG(Asrc, lda, 0, 1, 0, 0); STG(Bsrc, ldb, 1, 1, 0, 0);
  STG(Asrc, lda, 0, 0, 1, 1); STG(Bsrc, ldb, 1, 0, 1, 1);
  asm volatile("s_waitcnt vmcnt(4)" ::: "memory");
  __builtin_amdgcn_s_barrier();

  for (int g = 0; g < NT; ++g) {
    int buf = g & 1;
    int t1 = g + 1; if (t1 >= NT) t1 -= NT;   // wrapped prefetch stays in-bounds;
    int t2 = g + 2; if (t2 >= NT) t2 -= NT;   // wrapped data never read
    const char* _Al = lds + buf * 65536;
    const char* _Bl = _Al + 32768;
    bf16x8 af[4][2], b0[2][2], b1[2][2];

    // ---- p0: quadrant (0,0) ----
    READ_A(0);
    READ_BQ(b0, 0);
    STG(Asrc, lda, 0, 1, t1, buf ^ 1);
    __builtin_amdgcn_s_barrier();
    asm volatile("s_waitcnt lgkmcnt(0)" ::: "memory");
    __builtin_amdgcn_sched_barrier(0);
    __builtin_amdgcn_s_setprio(1);
    MFMA16(0, 0, b0);
    __builtin_amdgcn_s_setprio(0);
    __builtin_amdgcn_s_barrier();

    // ---- p1: quadrant (0,1) ----
    READ_BQ(b1, 1);
    STG(Bsrc, ldb, 1, 1, t1, buf ^ 1);
    __builtin_amdgcn_s_barrier();
    asm volatile("s_waitcnt lgkmcnt(0)" ::: "memory");
    __builtin_amdgcn_sched_barrier(0);
    __builtin_amdgcn_s_setprio(1);
    MFMA16(0, 1, b1);
    __builtin_amdgcn_s_setprio(0);
    __builtin_amdgcn_s_barrier();

    // ---- p2: quadrant (1,1) ----
    READ_A(1);
    STG(Asrc, lda, 0, 0, t2, buf);
    __builtin_amdgcn_s_barrier();
    asm volatile("s_waitcnt lgkmcnt(0)" ::: "memory");
    __builtin_amdgcn_sched_barrier(0);
    __builtin_amdgcn_s_setprio(1);
    MFMA16(1, 1, b1);
    __builtin_amdgcn_s_setprio(0);
    __builtin_amdgcn_s_barrier();

    // ---- p3: quadrant (1,0) -- no ds reads (b0 held in regs) ----
    STG(Bsrc, ldb, 1, 0, t2, buf);
    __builtin_amdgcn_s_barrier();
    __builtin_amdgcn_s_setprio(1);
    MFMA16(1, 0, b0);
    __builtin_amdgcn_s_setprio(0);
    asm volatile("s_waitcnt vmcnt(4)" ::: "memory");
    __builtin_amdgcn_s_barrier();
  }

  // epilogue: C/D frag mapping: row = base + lhi*4 + reg, col = base + l15
  int Mbase = bm * 256, Nbase = bn * 256;
#pragma unroll
  for (int qm = 0; qm < 2; ++qm)
#pragma unroll
    for (int qn = 0; qn < 2; ++qn)
#pragma unroll
      for (int i = 0; i < 4; ++i)
#pragma unroll
        for (int j = 0; j < 2; ++j) {
          int r0 = Mbase + qm * 128 + wm * 64 + i * 16 + lhi * 4;
          int col = Nbase + qn * 128 + wn * 32 + j * 16 + l15;
          f32x4 v = acc[qm][qn][i][j];
          if constexpr (CMODE == 0) {
            float* C = (float*)Cptr + (long)bz * sCz;
#pragma unroll
            for (int r = 0; r < 4; ++r)
              C[(long)(r0 + r) * ldc + col] = v[r];
          } else if constexpr (CMODE == 1) {
            u16* C = (u16*)Cptr + (long)bz * sCz;
#pragma unroll
            for (int r = 0; r < 4; ++r)
              C[(long)(r0 + r) * ldc + col] = f2bf(v[r]);
          } else {
            // fused QKV: cols [0,1024)=Q, [1024,2048)=K row-major bf16; [2048,3072)=V -> Vt[b][e][s]
            if (col < 2048) {
              u16* dst = (u16*)Cptr + (col >= 1024 ? 8388608 : 0);
              int c = col & 1023;
#pragma unroll
              for (int r = 0; r < 4; ++r)
                dst[(long)(r0 + r) * 1024 + c] = f2bf(v[r]);
            } else {
              u16* Vt = (u16*)Cptr + 16777216;
              int e = col - 2048;
              int bb = r0 >> 11, s = r0 & 2047;
              ushort4 u;
              u.x = f2bf(v[0]); u.y = f2bf(v[1]); u.z = f2bf(v[2]); u.w = f2bf(v[3]);
              *reinterpret_cast<ushort4*>(Vt + ((long)bb * 1024 + e) * 2048 + s) = u;
            }
          }
        }
}

// ---------------- one-pass causal row softmax: sc(bf16, unscaled) -> P(bf16) ----------------
__global__ __launch_bounds__(256) void softmax1p(const u16* __restrict__ sc,
                                                 u16* __restrict__ P) {
  int q = blockIdx.x, b = blockIdx.y;
  const u16* srow = sc + ((long)b * S_LEN + q) * S_LEN;
  u16* prow = P + ((long)b * S_LEN + q) * S_LEN;
  int n = q + 1;
  int nz = ((q >> 8) + 1) << 8;   // zero-fill bound (256-aligned)
  int tid = threadIdx.x;
  int j0 = tid * 8;
  const float scale = 0.03125f;   // 1/sqrt(1024)

  __shared__ float red[8];

  float vs[8];
#pragma unroll
  for (int e = 0; e < 8; ++e) vs[e] = -1e30f;
  if (j0 < n) {
    ushort4 a = *reinterpret_cast<const ushort4*>(srow + j0);
    ushort4 c = *reinterpret_cast<const ushort4*>(srow + j0 + 4);
    vs[0] = bf2f(a.x) * scale; vs[1] = bf2f(a.y) * scale;
    vs[2] = bf2f(a.z) * scale; vs[3] = bf2f(a.w) * scale;
    vs[4] = bf2f(c.x) * scale; vs[5] = bf2f(c.y) * scale;
    vs[6] = bf2f(c.z) * scale; vs[7] = bf2f(c.w) * scale;
#pragma unroll
    for (int e = 0; e < 8; ++e)
      if (j0 + e >= n) vs[e] = -1e30f;
  }

  float m = -1e30f;
#pragma unroll
  for (int e = 0; e < 8; ++e) m = fmaxf(m, vs[e]);
#pragma unroll
  for (int off = 32; off > 0; off >>= 1) m = fmaxf(m, __shfl_xor(m, off, 64));
  if ((tid & 63) == 0) red[tid >> 6] = m;
  __syncthreads();
  float ms = fmaxf(fmaxf(red[0], red[1]), fmaxf(red[2], red[3]));

  float p[8];
  float s = 0.f;
#pragma unroll
  for (int e = 0; e < 8; ++e) { p[e] = __expf(vs[e] - ms); s += (j0 + e < n) ? p[e] : 0.f; }
#pragma unroll
  for (int off = 32; off > 0; off >>= 1) s += __shfl_xor(s, off, 64);
  __syncthreads();
  if ((tid & 63) == 0) red[4 + (tid >> 6)] = s;
  __syncthreads();
  float inv = 1.f / (red[4] + red[5] + red[6] + red[7]);

  if (j0 < nz) {
    ushort4 o0, o1;
    o0.x = (j0 + 0 < n) ? f2bf(p[0] * inv) : (u16)0;
    o0.y = (j0 + 1 < n) ? f2bf(p[1] * inv) : (u16)0;
    o0.z = (j0 + 2 < n) ? f2bf(p[2] * inv) : (u16)0;
    o0.w = (j0 + 3 < n) ? f2bf(p[3] * inv) : (u16)0;
    o1.x = (j0 + 4 < n) ? f2bf(p[4] * inv) : (u16)0;
    o1.y = (j0 + 5 < n) ? f2bf(p[5] * inv) : (u16)0;
    o1.z = (j0 + 6 < n) ? f2bf(p[6] * inv) : (u16)0;
    o1.w = (j0 + 7 < n) ? f2bf(p[7] * inv) : (u16)0;
    *reinterpret_cast<ushort4*>(prow + j0) = o0;
    *reinterpret_cast<ushort4*>(prow + j0 + 4) = o1;
  }
}

// ---------------- launch ----------------
extern "C" void kernel_launch(void* const* d_in, const int* in_sizes, int n_in,
                              void* d_out, int out_size, void* d_ws, size_t ws_size,
                              hipStream_t stream) {
  const float* x  = (const float*)d_in[0];
  const float* Wq = (const float*)d_in[1];
  const float* Wk = (const float*)d_in[2];
  const float* Wv = (const float*)d_in[3];
  float* out = (float*)d_out;

  // workspace layout (bytes)
  char* ws = (char*)d_ws;
  u16* xb  = (u16*)(ws);                    // [8192][1024] bf16        : 16,777,216
  u16* wtb = (u16*)(ws + 16777216);         // [3072][1024] bf16 (W^T)  :  6,291,456
  u16* Qb  = (u16*)(ws + 23068672);         // [4][2048][1024] bf16     : 16,777,216
  u16* Kb  = (u16*)(ws + 39845888);         // [4][2048][1024] bf16
  u16* Vtb = (u16*)(ws + 56623104);         // [4][1024][2048] bf16
  u16* scb = (u16*)(ws + 73400320);         // [4][2048][2048] bf16     : 33,554,432
  u16* P   = (u16*)(ws + 106954752);        // [4][2048][2048] bf16     : 33,554,432

  long nx = (long)NBATCH * S_LEN * DMODEL;
  convert_x_kernel<<<2048, 256, 0, stream>>>(x, xb, nx);

  dim3 tb(32, 8);
  transpose_w_kernel<<<dim3(32, 32), tb, 0, stream>>>(Wq, wtb);
  transpose_w_kernel<<<dim3(32, 32), tb, 0, stream>>>(Wk, wtb + 1024 * 1024);
  transpose_w_kernel<<<dim3(32, 32), tb, 0, stream>>>(Wv, wtb + 2 * 1024 * 1024);

  // fused QKV projection: M=8192, N=3072 (Q|K|V), K=1024
  gemm256<3, 0><<<dim3(32, 12, 1), 512, 0, stream>>>(
      xb, wtb, Qb, DMODEL, DMODEL, 0, DMODEL, 0, 0, 0);

  // scores (unscaled, bf16): per batch S = Q*K^T, causal block skip
  gemm256<1, 1><<<dim3(8, 8, 4), 512, 0, stream>>>(
      Qb, Kb, scb, DMODEL, DMODEL, S_LEN, DMODEL,
      (long)S_LEN * DMODEL, (long)S_LEN * DMODEL, (long)S_LEN * S_LEN);

  softmax1p<<<dim3(S_LEN, NBATCH), 256, 0, stream>>>(scb, P);

  // O = P * V : A = P [2048][2048] bf16, B = Vt [1024][2048] bf16, K-limited
  gemm256<0, 2><<<dim3(8, 4, 4), 512, 0, stream>>>(
      P, Vtb, out, S_LEN, S_LEN, DMODEL, S_LEN,
      (long)S_LEN * S_LEN, (long)DMODEL * S_LEN, (long)S_LEN * DMODEL);
}